// Round 1
// baseline (9653.098 us; speedup 1.0000x reference)
//
#include <hip/hip_runtime.h>
#include <math.h>

constexpr int B = 2, C = 256, H = 64, W = 64, HW = H * W;
constexpr int N = 2048, OUT = 7, P = 49, FD = C * P; // 12544
constexpr int K1 = 1024, NC = 16;
constexpr float CLAMP_V = 4.135f, SCALE_V = 1.0f / 16.0f;

// ---------------- K0: features [B,C,H,W] -> featT [B,HW,C] ----------------
__global__ void k_transpose_feat(const float* __restrict__ in, float* __restrict__ out) {
    __shared__ float tile[32][33];
    const int b  = blockIdx.z;
    const int c0 = blockIdx.y * 32;
    const int p0 = blockIdx.x * 32;
    const int tx = threadIdx.x % 32, ty = threadIdx.x / 32; // ty 0..7
#pragma unroll
    for (int r = 0; r < 32; r += 8)
        tile[ty + r][tx] = in[(size_t)(b * C + c0 + ty + r) * HW + p0 + tx];
    __syncthreads();
#pragma unroll
    for (int r = 0; r < 32; r += 8)
        out[(size_t)(b * HW + p0 + ty + r) * C + c0 + tx] = tile[tx][ty + r];
}

// ---------------- K1: conv_w [co][ci*9+k] -> wT [ci*9+k][co] ----------------
__global__ void k_transpose_w(const float* __restrict__ in, float* __restrict__ out,
                              int rows, int cols) {
    __shared__ float tile[32][33];
    const int r0 = blockIdx.y * 32, c0 = blockIdx.x * 32;
    const int tx = threadIdx.x % 32, ty = threadIdx.x / 32;
#pragma unroll
    for (int r = 0; r < 32; r += 8) {
        int rr = r0 + ty + r, cc = c0 + tx;
        tile[ty + r][tx] = (rr < rows && cc < cols) ? in[(size_t)rr * cols + cc] : 0.f;
    }
    __syncthreads();
#pragma unroll
    for (int r = 0; r < 32; r += 8) {
        int cc = c0 + ty + r, rr = r0 + tx;
        if (cc < cols && rr < rows) out[(size_t)cc * rows + rr] = tile[tx][ty + r];
    }
}

// ------- K2: per-RoI mega kernel: roi_align -> conv+relu -> align GEMV -------
// -------     -> decode -> grid_sample ; box_feat lives in LDS          -------
__global__ __launch_bounds__(256, 2) void k_roi_conv_grid(
    const float* __restrict__ featT, const float* __restrict__ proposals,
    const int* __restrict__ bidx, const float* __restrict__ wT,
    const float* __restrict__ conv_b, const float* __restrict__ align_w,
    const float* __restrict__ align_b, float* __restrict__ alignedOut) {
    constexpr int LDP = 260; // padded row stride (floats): breaks bank clustering in grid phase
    __shared__ __align__(16) float bf[P * LDP];
    __shared__ float red[32];

    const int n = blockIdx.x;
    const int t = threadIdx.x; // channel / co

    // ---- phase 1: roi_align (sampling_ratio=1) into LDS, bf[p][c] ----
    const float px1 = proposals[n * 4 + 0] * SCALE_V, py1 = proposals[n * 4 + 1] * SCALE_V;
    const float px2 = proposals[n * 4 + 2] * SCALE_V, py2 = proposals[n * 4 + 3] * SCALE_V;
    const float bw = fmaxf(px2 - px1, 1.0f) * (1.0f / OUT);
    const float bh = fmaxf(py2 - py1, 1.0f) * (1.0f / OUT);
    const int b = bidx[n];
    const float* fb = featT + (size_t)b * HW * C;
    for (int p = 0; p < P; ++p) {
        const int pyi = p / 7, pxi = p % 7;
        float y = py1 + (pyi + 0.5f) * bh;
        float x = px1 + (pxi + 0.5f) * bw;
        y = fminf(fmaxf(y, 0.f), (float)(H - 1));
        x = fminf(fmaxf(x, 0.f), (float)(W - 1));
        const float y0f = floorf(y), x0f = floorf(x);
        const int y0 = (int)y0f, x0 = (int)x0f;
        const int y1 = min(y0 + 1, H - 1), x1 = min(x0 + 1, W - 1);
        const float wy1 = y - y0f, wx1 = x - x0f;
        const float wy0 = 1.f - wy1, wx0 = 1.f - wx1;
        const float v00 = fb[(size_t)(y0 * W + x0) * C + t];
        const float v01 = fb[(size_t)(y0 * W + x1) * C + t];
        const float v10 = fb[(size_t)(y1 * W + x0) * C + t];
        const float v11 = fb[(size_t)(y1 * W + x1) * C + t];
        bf[p * LDP + t] = wy0 * (wx0 * v00 + wx1 * v01) + wy1 * (wx0 * v10 + wx1 * v11);
    }
    __syncthreads();

    // ---- phase 2: 3x3 conv (scatter form, zero-pad == skip invalid taps) ----
    float acc[P];
    const float bias = conv_b[t];
#pragma unroll
    for (int p = 0; p < P; ++p) acc[p] = bias;

    for (int ci = 0; ci < C; ci += 4) {
        float wv[4][9];
#pragma unroll
        for (int q = 0; q < 4; ++q)
#pragma unroll
            for (int k = 0; k < 9; ++k)
                wv[q][k] = wT[(size_t)((ci + q) * 9 + k) * C + t];
#pragma unroll
        for (int pin = 0; pin < P; ++pin) {
            const int py = pin / 7, px = pin % 7;
            const float4 v = *reinterpret_cast<const float4*>(&bf[pin * LDP + ci]);
            const float vv[4] = {v.x, v.y, v.z, v.w};
#pragma unroll
            for (int dy = -1; dy <= 1; ++dy) {
#pragma unroll
                for (int dx = -1; dx <= 1; ++dx) {
                    const int oy = py - dy, ox = px - dx;
                    if (oy >= 0 && oy < 7 && ox >= 0 && ox < 7) {
                        const int k = (dy + 1) * 3 + (dx + 1);
                        const int o = oy * 7 + ox;
#pragma unroll
                        for (int q = 0; q < 4; ++q) acc[o] = fmaf(wv[q][k], vv[q], acc[o]);
                    }
                }
            }
        }
    }
#pragma unroll
    for (int p = 0; p < P; ++p) acc[p] = fmaxf(acc[p], 0.f);

    // ---- phase 3: align GEMV  coarse[j] = sum a[t*49+p] * align_w[j][t*49+p] ----
    float pc[5];
#pragma unroll
    for (int j = 0; j < 5; ++j) {
        float s = 0.f;
#pragma unroll
        for (int p = 0; p < P; ++p) s = fmaf(acc[p], align_w[(size_t)j * FD + t * P + p], s);
        pc[j] = s;
    }
#pragma unroll
    for (int j = 0; j < 5; ++j) {
        float s = pc[j];
#pragma unroll
        for (int off = 32; off; off >>= 1) s += __shfl_xor(s, off);
        pc[j] = s;
    }
    const int wave = t >> 6, lane = t & 63;
    if (lane == 0) {
#pragma unroll
        for (int j = 0; j < 5; ++j) red[wave * 5 + j] = pc[j];
    }
    __syncthreads();

    // ---- phase 4: decode -> grid params (thread 0) ----
    if (t == 0) {
        float coarse[5];
#pragma unroll
        for (int j = 0; j < 5; ++j) {
            float s = red[j] + red[5 + j] + red[10 + j] + red[15 + j] + align_b[j];
            coarse[j] = fminf(fmaxf(s, -CLAMP_V), CLAMP_V);
        }
        const float x1r = proposals[n * 4 + 0], y1r = proposals[n * 4 + 1];
        const float x2r = proposals[n * 4 + 2], y2r = proposals[n * 4 + 3];
        const float w = x2r - x1r, h = y2r - y1r;
        const float w2 = w * expf(coarse[2]);
        const float h2 = h * expf(coarse[3]);
        const float ang = coarse[4];
        const float cth = cosf(ang), sth = sinf(ang);
        const float sx = w2 * (1.0f / OUT), sy = h2 * (1.0f / OUT);
        red[20] = sx * cth;  // A
        red[21] = sy * sth;  // Bv
        red[22] = sx * sth;  // Cc
        red[23] = sy * cth;  // D
    }
    __syncthreads();
    const float gA = red[20], gB = red[21], gC = red[22], gD = red[23];

    // ---- phase 5: grid_sample(zeros) from LDS, write aligned[n][c*49+p] ----
    for (int i = 0; i < P; ++i) {
        const int f = t + 256 * i;
        const int c = f / 49;
        const int p = f - c * 49;
        const int pyi = p / 7, pxi = p % 7;
        const float xb = (2 * pxi + 1) * (1.0f / OUT) - 1.0f;
        const float yb = (2 * pyi + 1) * (1.0f / OUT) - 1.0f;
        const float gx = gA * xb - gB * yb;
        const float gy = gC * xb + gD * yb;
        const float ix = ((gx + 1.0f) * OUT - 1.0f) * 0.5f;
        const float iy = ((gy + 1.0f) * OUT - 1.0f) * 0.5f;
        const float x0f = floorf(ix), y0f = floorf(iy);
        const int x0 = (int)x0f, y0 = (int)y0f;
        const float wx1 = ix - x0f, wy1 = iy - y0f;
        const float wx0 = 1.f - wx1, wy0 = 1.f - wy1;
        float val = 0.f;
        if (y0 >= 0 && y0 < 7 && x0 >= 0 && x0 < 7)         val = fmaf(wy0 * wx0, bf[(y0 * 7 + x0) * LDP + c], val);
        if (y0 >= 0 && y0 < 7 && x0 + 1 >= 0 && x0 + 1 < 7) val = fmaf(wy0 * wx1, bf[(y0 * 7 + x0 + 1) * LDP + c], val);
        if (y0 + 1 >= 0 && y0 + 1 < 7 && x0 >= 0 && x0 < 7) val = fmaf(wy1 * wx0, bf[((y0 + 1) * 7 + x0) * LDP + c], val);
        if (y0 + 1 >= 0 && y0 + 1 < 7 && x0 + 1 >= 0 && x0 + 1 < 7)
                                                            val = fmaf(wy1 * wx1, bf[((y0 + 1) * 7 + x0 + 1) * LDP + c], val);
        alignedOut[(size_t)n * FD + f] = val;
    }
}

// ---------------- K3/K4: fp32 tiled GEMM  C = act(A[M,K] * Wt[Nn,K]^T + b) ----------------
template <int BM, int BN, int BK>
__global__ __launch_bounds__(256) void k_gemm_relu(
    const float* __restrict__ A, const float* __restrict__ Wt,
    const float* __restrict__ bias, float* __restrict__ Cout,
    int M, int Nn, int K, int doRelu) {
    __shared__ __align__(16) float As[BK][BM + 4];
    __shared__ __align__(16) float Ws[BK][BN + 4];
    const int nt = Nn / BN;
    const int bx = blockIdx.x % nt, by = blockIdx.x / nt;
    const int t = threadIdx.x;
    const int tx = t % 16, ty = t / 16;
    float acc[4][4] = {};
    for (int k0 = 0; k0 < K; k0 += BK) {
#pragma unroll
        for (int j = 0; j < (BM * BK) / (256 * 4); ++j) {
            const int q = t + 256 * j;
            const int row = q / (BK / 4), kq = (q % (BK / 4)) * 4;
            const float4 v = *reinterpret_cast<const float4*>(&A[(size_t)(by * BM + row) * K + k0 + kq]);
            As[kq + 0][row] = v.x; As[kq + 1][row] = v.y; As[kq + 2][row] = v.z; As[kq + 3][row] = v.w;
        }
#pragma unroll
        for (int j = 0; j < (BN * BK) / (256 * 4); ++j) {
            const int q = t + 256 * j;
            const int row = q / (BK / 4), kq = (q % (BK / 4)) * 4;
            const float4 v = *reinterpret_cast<const float4*>(&Wt[(size_t)(bx * BN + row) * K + k0 + kq]);
            Ws[kq + 0][row] = v.x; Ws[kq + 1][row] = v.y; Ws[kq + 2][row] = v.z; Ws[kq + 3][row] = v.w;
        }
        __syncthreads();
#pragma unroll
        for (int kk = 0; kk < BK; ++kk) {
            const float4 a4 = *reinterpret_cast<const float4*>(&As[kk][ty * 4]);
            const float4 w4 = *reinterpret_cast<const float4*>(&Ws[kk][tx * 4]);
            const float av[4] = {a4.x, a4.y, a4.z, a4.w};
            const float wv[4] = {w4.x, w4.y, w4.z, w4.w};
#pragma unroll
            for (int i = 0; i < 4; ++i)
#pragma unroll
                for (int j = 0; j < 4; ++j) acc[i][j] = fmaf(av[i], wv[j], acc[i][j]);
        }
        __syncthreads();
    }
#pragma unroll
    for (int i = 0; i < 4; ++i) {
        const int row = by * BM + ty * 4 + i;
#pragma unroll
        for (int j = 0; j < 4; ++j) {
            const int col = bx * BN + tx * 4 + j;
            float v = acc[i][j] + bias[col];
            if (doRelu) v = fmaxf(v, 0.f);
            Cout[(size_t)row * Nn + col] = v;
        }
    }
}

// ---------------- K5: heads (cls/box GEMV + softmax + decode) ----------------
__global__ void k_heads(const float* __restrict__ r2, const float* __restrict__ cls_w,
                        const float* __restrict__ cls_b, const float* __restrict__ box_w,
                        const float* __restrict__ box_b, const float* __restrict__ proposals,
                        float* __restrict__ out) {
    const int n = blockIdx.x;
    const int t = threadIdx.x; // 64 lanes
    const float* r = r2 + (size_t)n * K1;
    float rv[16];
#pragma unroll
    for (int j = 0; j < 16; ++j) rv[j] = r[t + 64 * j];
    float s[21];
#pragma unroll
    for (int o = 0; o < 21; ++o) {
        const float* w = (o < 16) ? (cls_w + (size_t)o * K1) : (box_w + (size_t)(o - 16) * K1);
        float a = 0.f;
#pragma unroll
        for (int j = 0; j < 16; ++j) a = fmaf(rv[j], w[t + 64 * j], a);
#pragma unroll
        for (int off = 32; off; off >>= 1) a += __shfl_xor(a, off);
        s[o] = a;
    }
    float logits[16];
    float m = -1e30f;
#pragma unroll
    for (int o = 0; o < 16; ++o) { logits[o] = s[o] + cls_b[o]; m = fmaxf(m, logits[o]); }
    float es = 0.f;
#pragma unroll
    for (int o = 0; o < 16; ++o) { logits[o] = expf(logits[o] - m); es += logits[o]; }
    const float inv = 1.0f / es;
    float fdelta[5];
#pragma unroll
    for (int j = 0; j < 5; ++j) fdelta[j] = fminf(fmaxf(s[16 + j] + box_b[j], -CLAMP_V), CLAMP_V);
    const float x1r = proposals[n * 4 + 0], y1r = proposals[n * 4 + 1];
    const float x2r = proposals[n * 4 + 2], y2r = proposals[n * 4 + 3];
    const float cx = (x1r + x2r) * 0.5f, cy = (y1r + y2r) * 0.5f;
    const float w = x2r - x1r, h = y2r - y1r;
    float pred[5];
    pred[0] = cx + fdelta[0] * w;
    pred[1] = cy + fdelta[1] * h;
    pred[2] = w * expf(fdelta[2]);
    pred[3] = h * expf(fdelta[3]);
    pred[4] = fdelta[4];
    float* orow = out + (size_t)n * 21;
#pragma unroll
    for (int o = 0; o < 5; ++o)
        if (t == o) orow[o] = pred[o];
#pragma unroll
    for (int o = 0; o < 16; ++o)
        if (t == 5 + o) orow[5 + o] = logits[o] * inv;
}

extern "C" void kernel_launch(void* const* d_in, const int* in_sizes, int n_in,
                              void* d_out, int out_size, void* d_ws, size_t ws_size,
                              hipStream_t stream) {
    (void)in_sizes; (void)n_in; (void)out_size; (void)ws_size;
    const float* features  = (const float*)d_in[0];
    const float* proposals = (const float*)d_in[1];
    const int*   batch_idx = (const int*)d_in[2];
    const float* conv_w    = (const float*)d_in[3];
    const float* conv_b    = (const float*)d_in[4];
    const float* align_w   = (const float*)d_in[5];
    const float* align_b   = (const float*)d_in[6];
    const float* fc1_w     = (const float*)d_in[7];
    const float* fc1_b     = (const float*)d_in[8];
    const float* fc2_w     = (const float*)d_in[9];
    const float* fc2_b     = (const float*)d_in[10];
    const float* cls_w     = (const float*)d_in[11];
    const float* cls_b     = (const float*)d_in[12];
    const float* box_w     = (const float*)d_in[13];
    const float* box_b     = (const float*)d_in[14];
    float* out = (float*)d_out;

    float* ws      = (float*)d_ws;
    float* featT   = ws;                          // B*HW*C       = 2,097,152
    float* wT      = featT + (size_t)B * HW * C;  // 2304*256     =   589,824
    float* aligned = wT + 2304 * 256;             // N*FD         = 25,690,112
    float* r1      = aligned + (size_t)N * FD;    // N*K1         = 2,097,152
    float* r2      = r1 + (size_t)N * K1;         // N*K1         = 2,097,152
                                                  // total ~124 MiB

    k_transpose_feat<<<dim3(HW / 32, C / 32, B), 256, 0, stream>>>(features, featT);
    k_transpose_w<<<dim3(2304 / 32, 256 / 32), 256, 0, stream>>>(conv_w, wT, 256, 2304);
    k_roi_conv_grid<<<N, 256, 0, stream>>>(featT, proposals, batch_idx, wT, conv_b,
                                           align_w, align_b, aligned);
    k_gemm_relu<64, 64, 32><<<(N / 64) * (K1 / 64), 256, 0, stream>>>(aligned, fc1_w, fc1_b, r1, N, K1, FD, 1);
    k_gemm_relu<64, 64, 32><<<(N / 64) * (K1 / 64), 256, 0, stream>>>(r1, fc2_w, fc2_b, r2, N, K1, K1, 1);
    k_heads<<<N, 64, 0, stream>>>(r2, cls_w, cls_b, box_w, box_b, proposals, out);
}